// Round 18
// baseline (1034.556 us; speedup 1.0000x reference)
//
#include <hip/hip_runtime.h>

// Problem constants (match reference)
#define SEQ 2048
#define BAT 256
#define KD  64
#define HD  128
#define SBH 67108864u   // SEQ*BAT*HD

typedef _Float16 half2v  __attribute__((ext_vector_type(2)));  // fdot2 operand type
typedef __fp16   fp16x2  __attribute__((ext_vector_type(2)));  // cvt_pkrtz return type

// Pack two f32 -> f16x2 bits (v_cvt_pkrtz_f16_f32).
__device__ __forceinline__ int PK(float a, float b) {
    fp16x2 p = __builtin_amdgcn_cvt_pkrtz(a, b);
    return __builtin_bit_cast(int, p);
}

// f32 += dot2(f16x2, f16x2) — v_dot2_f32_f16, f32 accumulate.
__device__ __forceinline__ float fdot2(int w, int h, float c) {
#if __has_builtin(__builtin_amdgcn_fdot2)
    return __builtin_amdgcn_fdot2(__builtin_bit_cast(half2v, w),
                                  __builtin_bit_cast(half2v, h), c, false);
#else
    half2v wv = __builtin_bit_cast(half2v, w), hv = __builtin_bit_cast(half2v, h);
    return fmaf((float)wv[1], (float)hv[1], fmaf((float)wv[0], (float)hv[0], c));
#endif
}

// Pin a scalar into a register (loads can't sink past the volatile asm).
#define PIN(x) asm volatile("" : "+v"(x))
#define PIN4(v4) PIN(v4.x); PIN(v4.y); PIN(v4.z); PIN(v4.w)

// LDS-visibility-only barrier: does NOT drain vmcnt (output stores stay in
// flight; the loop has NO VMEM loads, so vmcnt is never waited on).
#define STEP_BARRIER() do {                                   \
    asm volatile("s_waitcnt lgkmcnt(0)" ::: "memory");        \
    __builtin_amdgcn_s_barrier();                             \
    asm volatile("" ::: "memory");                            \
} while (0)

// ---------------------------------------------------------------------------
// Kernel 1: precompute type-dependent tables into d_ws (f32).
//   tabH[ty][r] = sum_k embed_W[ty][k]*W_ih[r][k] + b_ih[r] + b_hh[r]
//   tabD[ty][r] = sum_k embed_W[ty][k]*dec_W[r][k] + dec_b[r]
// ---------------------------------------------------------------------------
__global__ __launch_bounds__(128) void precompute_tables(
    const float* __restrict__ embed_W, const float* __restrict__ W_ih,
    const float* __restrict__ b_ih,    const float* __restrict__ b_hh,
    const float* __restrict__ dec_W,   const float* __restrict__ dec_b,
    float* __restrict__ tabH, float* __restrict__ tabD)
{
    __shared__ float x[KD];
    const int ty = blockIdx.x;   // 0..64 (row 64 = padding, embed row is zero)
    const int r  = threadIdx.x;  // 0..127
    if (r < KD) x[r] = embed_W[ty * KD + r];
    __syncthreads();
    float ah = 0.f, ad = 0.f;
#pragma unroll
    for (int k = 0; k < KD; ++k) {
        const float xv = x[k];
        ah += xv * W_ih[r * KD + k];
        ad += xv * dec_W[r * (KD + HD) + k];
    }
    tabH[ty * HD + r] = ah + b_ih[r] + b_hh[r];
    tabD[ty * HD + r] = ad + dec_b[r];
}

// ---------------------------------------------------------------------------
// Kernel 2: persistent per-batch-element recurrence. One WG per batch elem,
// 128 threads = 2 WAVES. Lane r (= tid) owns output row r COMPLETELY:
// computes hidden[r] AND decay[r] over the full K=128 — NO cross-lane
// reduction, NO type exchange, NO duplicated activation work (r17 analysis:
// epilogue issue was ~2x duplicated across 4 waves and the reduction+exchange
// existed only because K was lane-split).
// h is read as wave-uniform BROADCAST ds_read_b128 (all lanes same address ->
// LDS fast path, conflict-free), interleaved with dot blocks in 4 batches so
// LDS latency pipelines under fdot2 issue.
// Per lane per step: 16 broadcast h reads, 128 fdot2 (4-way split chains),
// one real activation pair, hnew = vh*vd in-lane, 3 global stores, 1 LDS
// h-write (lane r writes h16[^1][r]). One lgkm-only barrier; 2x unrolled.
// Tables in LDS f16 (r17) -> loop has zero VMEM loads.
// ---------------------------------------------------------------------------
__global__ __launch_bounds__(128, 1) void hawkes_rnn(
    const float* __restrict__ dt_g,  const float* __restrict__ h0,
    const float* __restrict__ W_hh,  const float* __restrict__ dec_W,
    const int*   __restrict__ seq_types,
    const float* __restrict__ tabH,  const float* __restrict__ tabD,
    float* __restrict__ out)
{
    __shared__ __align__(16) _Float16 h16[2][HD];       //    512 B
    __shared__ __align__(8) int2 dtty[SEQ + 2];         // 16,400 B {dt, ty}
    __shared__ _Float16 tabLH[(KD + 1) * HD];           // 16,640 B
    __shared__ _Float16 tabLD[(KD + 1) * HD];           // 16,640 B (tot ~50 KB)

    const int b   = blockIdx.x;
    const int tid = threadIdx.x;     // 0..127
    const int row = tid;             // output row this lane owns

    // Stage packed {dt, ty} pairs + both bias tables (f32 -> f16) + h0.
    for (int t = tid; t < SEQ; t += 128) {
        dtty[t] = make_int2(__float_as_int(dt_g[(size_t)t * BAT + b]),
                            seq_types[(size_t)t * BAT + b]);
    }
    if (tid < 2) dtty[SEQ + tid] = make_int2(0, 0);   // prefetch-pad
    for (int i = tid; i < (KD + 1) * HD; i += 128) {
        tabLH[i] = (_Float16)tabH[i];
        tabLD[i] = (_Float16)tabD[i];
    }
    h16[0][tid] = (_Float16)h0[b * HD + tid];

    // Load + convert this lane's TWO weight rows (full K=128 each) to f16x2:
    // W_hh[row][0..127] and dec_W[row][KD..KD+127] -> 16 + 16 named int4.
    const float* wh = W_hh  + (size_t)row * HD;
    const float* wd = dec_W + (size_t)row * (KD + HD) + KD;
#define LQ(D, P) { \
    const float4 _a = *reinterpret_cast<const float4*>(P);       \
    const float4 _b = *reinterpret_cast<const float4*>((P) + 4); \
    D = make_int4(PK(_a.x,_a.y), PK(_a.z,_a.w), PK(_b.x,_b.y), PK(_b.z,_b.w)); }
    int4 wh0,wh1,wh2,wh3,wh4,wh5,wh6,wh7,wh8,wh9,wh10,wh11,wh12,wh13,wh14,wh15;
    int4 wd0,wd1,wd2,wd3,wd4,wd5,wd6,wd7,wd8,wd9,wd10,wd11,wd12,wd13,wd14,wd15;
    LQ(wh0,  wh +   0) LQ(wh1,  wh +   8) LQ(wh2,  wh +  16) LQ(wh3,  wh +  24)
    LQ(wh4,  wh +  32) LQ(wh5,  wh +  40) LQ(wh6,  wh +  48) LQ(wh7,  wh +  56)
    LQ(wh8,  wh +  64) LQ(wh9,  wh +  72) LQ(wh10, wh +  80) LQ(wh11, wh +  88)
    LQ(wh12, wh +  96) LQ(wh13, wh + 104) LQ(wh14, wh + 112) LQ(wh15, wh + 120)
    LQ(wd0,  wd +   0) LQ(wd1,  wd +   8) LQ(wd2,  wd +  16) LQ(wd3,  wd +  24)
    LQ(wd4,  wd +  32) LQ(wd5,  wd +  40) LQ(wd6,  wd +  48) LQ(wd7,  wd +  56)
    LQ(wd8,  wd +  64) LQ(wd9,  wd +  72) LQ(wd10, wd +  80) LQ(wd11, wd +  88)
    LQ(wd12, wd +  96) LQ(wd13, wd + 104) LQ(wd14, wd + 112) LQ(wd15, wd + 120)
#undef LQ
    PIN4(wh0); PIN4(wh1); PIN4(wh2); PIN4(wh3);
    PIN4(wh4); PIN4(wh5); PIN4(wh6); PIN4(wh7);
    PIN4(wh8); PIN4(wh9); PIN4(wh10);PIN4(wh11);
    PIN4(wh12);PIN4(wh13);PIN4(wh14);PIN4(wh15);
    PIN4(wd0); PIN4(wd1); PIN4(wd2); PIN4(wd3);
    PIN4(wd4); PIN4(wd5); PIN4(wd6); PIN4(wd7);
    PIN4(wd8); PIN4(wd9); PIN4(wd10);PIN4(wd11);
    PIN4(wd12);PIN4(wd13);PIN4(wd14);PIN4(wd15);

    // Per-lane element offset of row `row` in the hidden plane.
    unsigned off = (unsigned)(b * HD + row);

    __syncthreads();   // staging visible

    // Pipelines: (dt,ty) pair and the two LDS tab reads, 2 steps ahead.
    int2 pr_cur = dtty[0];
    int2 pr_nxt = dtty[1];
    float tabH_cur = (float)tabLH[pr_cur.y * HD + row];
    float tabD_cur = (float)tabLD[pr_cur.y * HD + row];
    float tabH_nxt = (float)tabLH[pr_nxt.y * HD + row];
    float tabD_nxt = (float)tabLD[pr_nxt.y * HD + row];

// One h-batch: read 4 broadcast int4 (32 f16 of h) and dot into the 4-way
// split accumulators for both matrices.
#define HBATCH(I0, WH_A, WH_B, WH_C, WH_D, WD_A, WD_B, WD_C, WD_D, AH, AD) { \
    const int4 hA = hsrc[(I0) + 0]; \
    const int4 hB = hsrc[(I0) + 1]; \
    const int4 hC = hsrc[(I0) + 2]; \
    const int4 hD = hsrc[(I0) + 3]; \
    AH = fdot2(WH_A.x, hA.x, AH); AH = fdot2(WH_A.y, hA.y, AH); \
    AH = fdot2(WH_A.z, hA.z, AH); AH = fdot2(WH_A.w, hA.w, AH); \
    AD = fdot2(WD_A.x, hA.x, AD); AD = fdot2(WD_A.y, hA.y, AD); \
    AD = fdot2(WD_A.z, hA.z, AD); AD = fdot2(WD_A.w, hA.w, AD); \
    AH = fdot2(WH_B.x, hB.x, AH); AH = fdot2(WH_B.y, hB.y, AH); \
    AH = fdot2(WH_B.z, hB.z, AH); AH = fdot2(WH_B.w, hB.w, AH); \
    AD = fdot2(WD_B.x, hB.x, AD); AD = fdot2(WD_B.y, hB.y, AD); \
    AD = fdot2(WD_B.z, hB.z, AD); AD = fdot2(WD_B.w, hB.w, AD); \
    AH = fdot2(WH_C.x, hC.x, AH); AH = fdot2(WH_C.y, hC.y, AH); \
    AH = fdot2(WH_C.z, hC.z, AH); AH = fdot2(WH_C.w, hC.w, AH); \
    AD = fdot2(WD_C.x, hC.x, AD); AD = fdot2(WD_C.y, hC.y, AD); \
    AD = fdot2(WD_C.z, hC.z, AD); AD = fdot2(WD_C.w, hC.w, AD); \
    AH = fdot2(WH_D.x, hD.x, AH); AH = fdot2(WH_D.y, hD.y, AH); \
    AH = fdot2(WH_D.z, hD.z, AH); AH = fdot2(WH_D.w, hD.w, AH); \
    AD = fdot2(WD_D.x, hD.x, AD); AD = fdot2(WD_D.y, hD.y, AD); \
    AD = fdot2(WD_D.z, hD.z, AD); AD = fdot2(WD_D.w, hD.w, AD); \
}

#define STEP(P, TT) { \
    const int2 pr_pf = dtty[(TT) + 2]; \
    const float tabH_pf = (float)tabLH[pr_pf.y * HD + row]; \
    const float tabD_pf = (float)tabLD[pr_pf.y * HD + row]; \
    const float dtv = __int_as_float(pr_cur.x); \
    const int4* hsrc = reinterpret_cast<const int4*>(&h16[P][0]); \
    float aH0 = 0.f, aH1 = 0.f, aH2 = 0.f, aH3 = 0.f; \
    float aD0 = 0.f, aD1 = 0.f, aD2 = 0.f, aD3 = 0.f; \
    HBATCH(0,  wh0, wh1, wh2, wh3,  wd0, wd1, wd2, wd3,  aH0, aD0) \
    HBATCH(4,  wh4, wh5, wh6, wh7,  wd4, wd5, wd6, wd7,  aH1, aD1) \
    HBATCH(8,  wh8, wh9, wh10,wh11, wd8, wd9, wd10,wd11, aH2, aD2) \
    HBATCH(12, wh12,wh13,wh14,wh15, wd12,wd13,wd14,wd15, aH3, aD3) \
    const float svH = (aH0 + aH1) + (aH2 + aH3) + tabH_cur; \
    const float svD = (aD0 + aD1) + (aD2 + aD3) + tabD_cur; \
    /* activations — all REAL work, no lane duplication */ \
    const float e2 = __expf(2.f * svH); \
    const float vh = 1.f - __fdividef(2.f, e2 + 1.f);            /* tanh */ \
    const float z  = 10.f * svD; \
    const float em = __expf(-fabsf(z)); \
    const float sp = 0.1f * (fmaxf(z, 0.f) + __logf(1.f + em));  /* softplus10 */ \
    const float vd = __expf(-sp * dtv); \
    const float hnew = vh * vd;          /* in-lane, no exchange */ \
    h16[(P) ^ 1][row] = (_Float16)hnew;  /* LDS write first (chain tail) */ \
    out[off] = vh; \
    out[off + SBH] = sp; \
    out[off + 2u * SBH] = hnew; \
    off += BAT * HD; \
    pr_cur = pr_nxt;     pr_nxt = pr_pf; \
    tabH_cur = tabH_nxt; tabH_nxt = tabH_pf; \
    tabD_cur = tabD_nxt; tabD_nxt = tabD_pf; \
    STEP_BARRIER(); \
}

    for (int t = 0; t < SEQ; t += 2) {
        STEP(0, t)
        STEP(1, t + 1)
    }
#undef STEP
#undef HBATCH
}

extern "C" void kernel_launch(void* const* d_in, const int* in_sizes, int n_in,
                              void* d_out, int out_size, void* d_ws, size_t ws_size,
                              hipStream_t stream) {
    const float* dt        = (const float*)d_in[0];
    const float* h0        = (const float*)d_in[1];
    const float* embed_W   = (const float*)d_in[2];
    const float* W_ih      = (const float*)d_in[3];
    const float* b_ih      = (const float*)d_in[4];
    const float* W_hh      = (const float*)d_in[5];
    const float* b_hh      = (const float*)d_in[6];
    const float* dec_W     = (const float*)d_in[7];
    const float* dec_b     = (const float*)d_in[8];
    const int*   seq_types = (const int*)  d_in[9];
    float* out  = (float*)d_out;

    float* tabHw = (float*)d_ws;                 // [65][128]
    float* tabDw = tabHw + (KD + 1) * HD;        // [65][128]

    precompute_tables<<<KD + 1, 128, 0, stream>>>(embed_W, W_ih, b_ih, b_hh,
                                                  dec_W, dec_b, tabHw, tabDw);
    hawkes_rnn<<<BAT, 128, 0, stream>>>(dt, h0, W_hh, dec_W, seq_types,
                                        tabHw, tabDw, out);
}

// Round 19
// 799.445 us; speedup vs baseline: 1.2941x; 1.2941x over previous
//
#include <hip/hip_runtime.h>

// Problem constants (match reference)
#define SEQ 2048
#define BAT 256
#define KD  64
#define HD  128
#define SBH 67108864u   // SEQ*BAT*HD

typedef _Float16 half2v  __attribute__((ext_vector_type(2)));  // fdot2 operand type
typedef __fp16   fp16x2  __attribute__((ext_vector_type(2)));  // cvt_pkrtz return type
typedef unsigned uint2v  __attribute__((ext_vector_type(2)));  // permlane32_swap ret

// DPP helpers — ALL direction-proof: 0xB1 = quad_perm(1,0,3,2) = lane^1;
// 0x4E = quad_perm(2,3,0,1) = lane^2; 0x128 = row_ror:8 = lane^8 within a
// 16-lane row (rotation by half the row = involution either direction).
template<int CTRL>
__device__ __forceinline__ float dpp_add(float keep, float send) {
    const int r = __builtin_amdgcn_update_dpp(0, __float_as_int(send),
                                              CTRL, 0xF, 0xF, true);
    return keep + __int_as_float(r);
}

// lane^32 exchange via v_permlane32_swap_b32 (VALU pipe; self-symmetric).
__device__ __forceinline__ float xchg32(float v, int hi_half, int lane) {
#if __has_builtin(__builtin_amdgcn_permlane32_swap)
    uint2v r = __builtin_amdgcn_permlane32_swap(__float_as_uint(v),
                                                __float_as_uint(v),
                                                false, false);
    return __uint_as_float(hi_half ? r.x : r.y);
#else
    return __uint_as_float(__builtin_amdgcn_ds_bpermute(
        ((lane ^ 32) << 2), __float_as_uint(v)));
#endif
}

// Pack two f32 -> f16x2 bits (v_cvt_pkrtz_f16_f32).
__device__ __forceinline__ int PK(float a, float b) {
    fp16x2 p = __builtin_amdgcn_cvt_pkrtz(a, b);
    return __builtin_bit_cast(int, p);
}

// f32 += dot2(f16x2, f16x2) — v_dot2_f32_f16, f32 accumulate.
__device__ __forceinline__ float fdot2(int w, int h, float c) {
#if __has_builtin(__builtin_amdgcn_fdot2)
    return __builtin_amdgcn_fdot2(__builtin_bit_cast(half2v, w),
                                  __builtin_bit_cast(half2v, h), c, false);
#else
    half2v wv = __builtin_bit_cast(half2v, w), hv = __builtin_bit_cast(half2v, h);
    return fmaf((float)wv[1], (float)hv[1], fmaf((float)wv[0], (float)hv[0], c));
#endif
}

// Pin a scalar into a register (loads can't sink past the volatile asm).
#define PIN(x) asm volatile("" : "+v"(x))
#define PIN4(v4) PIN(v4.x); PIN(v4.y); PIN(v4.z); PIN(v4.w)

// LDS-visibility-only barrier: does NOT drain vmcnt (output stores stay in
// flight; the loop has NO VMEM loads, so vmcnt is never waited on).
#define STEP_BARRIER() do {                                   \
    asm volatile("s_waitcnt lgkmcnt(0)" ::: "memory");        \
    __builtin_amdgcn_s_barrier();                             \
    asm volatile("" ::: "memory");                            \
} while (0)

// ---------------------------------------------------------------------------
// Kernel 1: precompute type-dependent tables into d_ws (f32).
//   tabH[ty][r] = sum_k embed_W[ty][k]*W_ih[r][k] + b_ih[r] + b_hh[r]
//   tabD[ty][r] = sum_k embed_W[ty][k]*dec_W[r][k] + dec_b[r]
// ---------------------------------------------------------------------------
__global__ __launch_bounds__(128) void precompute_tables(
    const float* __restrict__ embed_W, const float* __restrict__ W_ih,
    const float* __restrict__ b_ih,    const float* __restrict__ b_hh,
    const float* __restrict__ dec_W,   const float* __restrict__ dec_b,
    float* __restrict__ tabH, float* __restrict__ tabD)
{
    __shared__ float x[KD];
    const int ty = blockIdx.x;   // 0..64 (row 64 = padding, embed row is zero)
    const int r  = threadIdx.x;  // 0..127
    if (r < KD) x[r] = embed_W[ty * KD + r];
    __syncthreads();
    float ah = 0.f, ad = 0.f;
#pragma unroll
    for (int k = 0; k < KD; ++k) {
        const float xv = x[k];
        ah += xv * W_ih[r * KD + k];
        ad += xv * dec_W[r * (KD + HD) + k];
    }
    tabH[ty * HD + r] = ah + b_ih[r] + b_hh[r];
    tabD[ty * HD + r] = ad + dec_b[r];
}

// ---------------------------------------------------------------------------
// Kernel 2: persistent per-batch-element recurrence. One WG per batch elem,
// 256 threads = 4 waves (r17 structure, best 824us). Round-19 changes:
//  1. SELECT-FREE reduction: weight slot s holds row 8G + (r0 ^ s) where
//     r0 = 4b0+2b1+b3. Every butterfly stage is then a plain
//     t_s = a_s + dpp(a_{s+4}) — the xor-partner's slot s+4 holds the SAME
//     row (lane^1 flips b0 only, lane^2 flips b1, lane^8 flips b3). Zero
//     cndmask in the reduction; final owned row unchanged (slot 0 = r17 row).
//  2. Stores AFTER the barrier: the 3 global stores are carried in regs and
//     issued at the top of the next step, overlapping the h ds_read latency
//     instead of sitting in the pre-barrier chain.
// Lane bits: b0,b1,b3 = chunk bits (and xor-resolved row bits); b2,b4 static
// row bits; b5 = type (0=hidden, 1=decay). G = wave*4 + b4*2 + b2.
// chunk = b0|b1<<1|b3<<2; row = 8G + 4b0+2b1+b3. 64 fdot2/lane.
// Tables in LDS f16 -> loop has zero VMEM loads. One lgkm-only barrier/step.
// ---------------------------------------------------------------------------
__global__ __launch_bounds__(256, 1) void hawkes_rnn(
    const float* __restrict__ dt_g,  const float* __restrict__ h0,
    const float* __restrict__ W_hh,  const float* __restrict__ dec_W,
    const int*   __restrict__ seq_types,
    const float* __restrict__ tabH,  const float* __restrict__ tabD,
    float* __restrict__ out)
{
    __shared__ __align__(16) _Float16 h16[2][HD];       //    512 B
    __shared__ __align__(8) int2 dtty[SEQ + 2];         // 16,400 B {dt, ty}
    __shared__ _Float16 tabLH[(KD + 1) * HD];           // 16,640 B
    __shared__ _Float16 tabLD[(KD + 1) * HD];           // 16,640 B (tot ~50 KB)

    const int b    = blockIdx.x;
    const int tid  = threadIdx.x;
    const int lane = tid & 63;
    const int b0 = lane & 1, b1 = (lane >> 1) & 1;
    const int b2 = (lane >> 2) & 1, b3 = (lane >> 3) & 1;
    const int b4 = (lane >> 4) & 1, b5 = (lane >> 5) & 1;
    const int G     = (tid >> 6) * 4 + b4 * 2 + b2;       // row octet 0..15
    const int r0_   = 4 * b0 + 2 * b1 + b3;               // xor-base within octet
    const int row   = 8 * G + r0_;                        // row this lane owns
    const int chunk = b0 | (b1 << 1) | (b3 << 2);         // h-col block /16

    // Stage packed {dt, ty} pairs + both bias tables (f32 -> f16) + h0.
    for (int t = tid; t < SEQ; t += 256) {
        dtty[t] = make_int2(__float_as_int(dt_g[(size_t)t * BAT + b]),
                            seq_types[(size_t)t * BAT + b]);
    }
    if (tid < 2) dtty[SEQ + tid] = make_int2(0, 0);   // prefetch-pad
    for (int i = tid; i < (KD + 1) * HD; i += 256) {
        tabLH[i] = (_Float16)tabH[i];
        tabLD[i] = (_Float16)tabD[i];
    }
    if (tid < HD) h16[0][tid] = (_Float16)h0[b * HD + tid];

    // Load + convert weight slots: slot s = row 8G + (r0_^s), cols
    // 16*chunk..+15 of this lane's type matrix -> 2 int4 (8 f16x2) per slot.
    const size_t rstr = b5 ? (size_t)(KD + HD) : (size_t)HD;
    const float* mat = (b5 ? (dec_W + KD) : W_hh);
#define LWROW(DA, DB, S) { \
    const float* _p = mat + (size_t)(8 * G + (r0_ ^ (S))) * rstr + chunk * 16; \
    const float4 _a = *reinterpret_cast<const float4*>(_p);        \
    const float4 _b = *reinterpret_cast<const float4*>(_p + 4);    \
    const float4 _c = *reinterpret_cast<const float4*>(_p + 8);    \
    const float4 _d = *reinterpret_cast<const float4*>(_p + 12);   \
    DA = make_int4(PK(_a.x,_a.y), PK(_a.z,_a.w), PK(_b.x,_b.y), PK(_b.z,_b.w)); \
    DB = make_int4(PK(_c.x,_c.y), PK(_c.z,_c.w), PK(_d.x,_d.y), PK(_d.z,_d.w)); }
    int4 w0a,w0b,w1a,w1b,w2a,w2b,w3a,w3b,w4a,w4b,w5a,w5b,w6a,w6b,w7a,w7b;
    LWROW(w0a,w0b, 0)  LWROW(w1a,w1b, 1)
    LWROW(w2a,w2b, 2)  LWROW(w3a,w3b, 3)
    LWROW(w4a,w4b, 4)  LWROW(w5a,w5b, 5)
    LWROW(w6a,w6b, 6)  LWROW(w7a,w7b, 7)
#undef LWROW
    PIN4(w0a); PIN4(w0b); PIN4(w1a); PIN4(w1b);
    PIN4(w2a); PIN4(w2b); PIN4(w3a); PIN4(w3b);
    PIN4(w4a); PIN4(w4b); PIN4(w5a); PIN4(w5b);
    PIN4(w6a); PIN4(w6b); PIN4(w7a); PIN4(w7b);

    const _Float16* tabp = (b5 ? tabLD : tabLH) + row;

    // Running element offset for this lane's store task (advances per store).
    unsigned off = (unsigned)(b * HD + row);

    __syncthreads();   // staging visible

    // Pipelines: (dt,ty) pair and LDS tab read, 2 steps ahead.
    int2 pr_cur = dtty[0];
    int2 pr_nxt = dtty[1];
    float tab_cur = (float)tabp[pr_cur.y * HD];
    float tab_nxt = (float)tabp[pr_nxt.y * HD];

    float stv_c = 0.f, hnew_c = 0.f;   // carried store values (prev step)

#define DOT16(A, WA, WB) \
    A = fdot2(WA.x, hv0.x, A); A = fdot2(WA.y, hv0.y, A); \
    A = fdot2(WA.z, hv0.z, A); A = fdot2(WA.w, hv0.w, A); \
    A = fdot2(WB.x, hv1.x, A); A = fdot2(WB.y, hv1.y, A); \
    A = fdot2(WB.z, hv1.z, A); A = fdot2(WB.w, hv1.w, A);

#define STEP(P, TT, DOST) { \
    /* h chunk reads FIRST (latency overlaps the carried stores below) */ \
    const int4 hv0 = *reinterpret_cast<const int4*>(&h16[P][chunk * 16]); \
    const int4 hv1 = *reinterpret_cast<const int4*>(&h16[P][chunk * 16 + 8]); \
    if (DOST) {                         /* stores of the PREVIOUS step */ \
        if (b5 == 0) { out[off] = stv_c; out[off + 2u * SBH] = hnew_c; } \
        else         { out[off + SBH] = stv_c; } \
        off += BAT * HD; \
    } \
    const int2 pr_pf = dtty[(TT) + 2];               /* one b64 read */ \
    const float tab_pf = (float)tabp[pr_pf.y * HD];  /* LDS read, use TT+2 */ \
    const float dtv = __int_as_float(pr_cur.x); \
    float a0 = 0.f, a1 = 0.f, a2 = 0.f, a3 = 0.f; \
    float a4 = 0.f, a5 = 0.f, a6 = 0.f, a7 = 0.f; \
    DOT16(a0, w0a, w0b)  DOT16(a1, w1a, w1b) \
    DOT16(a2, w2a, w2b)  DOT16(a3, w3a, w3b) \
    DOT16(a4, w4a, w4b)  DOT16(a5, w5a, w5b) \
    DOT16(a6, w6a, w6b)  DOT16(a7, w7a, w7b) \
    /* select-free butterfly: partner's slot s+4/s+2/s+1-group holds the */ \
    /* same row by construction (slot s = row 8G + (r0_^s)) */ \
    const float t0 = dpp_add<0xB1>(a0, a4); \
    const float t1 = dpp_add<0xB1>(a1, a5); \
    const float t2 = dpp_add<0xB1>(a2, a6); \
    const float t3 = dpp_add<0xB1>(a3, a7); \
    const float u0 = dpp_add<0x4E>(t0, t2); \
    const float u1 = dpp_add<0x4E>(t1, t3); \
    const float sv = dpp_add<0x128>(u0, u1) + tab_cur; \
    /* activations (branchless; all lanes both paths) */ \
    const float e2 = __expf(2.f * sv); \
    const float vh = 1.f - __fdividef(2.f, e2 + 1.f);            /* tanh */ \
    const float z  = 10.f * sv; \
    const float em = __expf(-fabsf(z)); \
    const float sp = 0.1f * (fmaxf(z, 0.f) + __logf(1.f + em));  /* softplus10 */ \
    const float vd = __expf(-sp * dtv); \
    const float v  = b5 ? vd : vh; \
    /* type exchange lane^32: permlane32_swap (VALU, self-symmetric) */ \
    const float cross = xchg32(v, b5, lane); \
    const float hnew  = v * cross; \
    if (b5 == 0) h16[(P) ^ 1][row] = (_Float16)hnew;   /* pre-barrier */ \
    stv_c  = b5 ? sp : v; \
    hnew_c = hnew; \
    pr_cur = pr_nxt;   pr_nxt = pr_pf; \
    tab_cur = tab_nxt; tab_nxt = tab_pf; \
    STEP_BARRIER(); \
}

    STEP(0, 0, 0)          // step 0: nothing carried yet
    STEP(1, 1, 1)          // step 1: stores step 0
    for (int t = 2; t < SEQ; t += 2) {
        STEP(0, t, 1)      // stores t-1
        STEP(1, t + 1, 1)  // stores t
    }
    // final stores: step SEQ-1 results
    if (b5 == 0) { out[off] = stv_c; out[off + 2u * SBH] = hnew_c; }
    else         { out[off + SBH] = stv_c; }
#undef STEP
#undef DOT16
}

extern "C" void kernel_launch(void* const* d_in, const int* in_sizes, int n_in,
                              void* d_out, int out_size, void* d_ws, size_t ws_size,
                              hipStream_t stream) {
    const float* dt        = (const float*)d_in[0];
    const float* h0        = (const float*)d_in[1];
    const float* embed_W   = (const float*)d_in[2];
    const float* W_ih      = (const float*)d_in[3];
    const float* b_ih      = (const float*)d_in[4];
    const float* W_hh      = (const float*)d_in[5];
    const float* b_hh      = (const float*)d_in[6];
    const float* dec_W     = (const float*)d_in[7];
    const float* dec_b     = (const float*)d_in[8];
    const int*   seq_types = (const int*)  d_in[9];
    float* out  = (float*)d_out;

    float* tabHw = (float*)d_ws;                 // [65][128]
    float* tabDw = tabHw + (KD + 1) * HD;        // [65][128]

    precompute_tables<<<KD + 1, 128, 0, stream>>>(embed_W, W_ih, b_ih, b_hh,
                                                  dec_W, dec_b, tabHw, tabDw);
    hawkes_rnn<<<BAT, 256, 0, stream>>>(dt, h0, W_hh, dec_W, seq_types,
                                        tabHw, tabDw, out);
}